// Round 3
// baseline (1024.837 us; speedup 1.0000x reference)
//
#include <hip/hip_runtime.h>

typedef unsigned short u16;
typedef unsigned int u32;
typedef short short8 __attribute__((ext_vector_type(8)));
typedef float floatx4 __attribute__((ext_vector_type(4)));

__device__ __forceinline__ u16 f2bf(float x) {
    u32 u = __float_as_uint(x);
    u += 0x7fffu + ((u >> 16) & 1u);
    return (u16)(u >> 16);
}

// ---------------- diagnostic: zero the output (fp32) ----------------
__global__ void zero_out_k(float* __restrict__ out, int n) {
    int i = blockIdx.x * 256 + threadIdx.x;
    if (i < n) out[i] = 0.f;
}

// ---------------- CSR build: histogram, scan, scatter ----------------

__global__ void hist_k(const int* __restrict__ dst, int* __restrict__ cnt, int E, int N) {
    int e = blockIdx.x * 256 + threadIdx.x;
    if (e < E) {
        int d = dst[e];
        d = d < 0 ? 0 : (d >= N ? N - 1 : d);
        atomicAdd(&cnt[d], 1);
    }
}

__global__ void scan1_k(const int* __restrict__ cnt, int* __restrict__ excl,
                        int* __restrict__ aux, int N) {
    __shared__ int tmp[1024];
    int t = threadIdx.x;
    int i = blockIdx.x * 1024 + t;
    int v = (i < N) ? cnt[i] : 0;
    tmp[t] = v;
    __syncthreads();
    for (int off = 1; off < 1024; off <<= 1) {
        int x = (t >= off) ? tmp[t - off] : 0;
        __syncthreads();
        tmp[t] += x;
        __syncthreads();
    }
    if (i < N) excl[i] = tmp[t] - v;
    if (t == 1023) aux[blockIdx.x] = tmp[t];
}

__global__ void scan2_k(int* __restrict__ aux, int nb) {
    int lane = threadIdx.x;  // single block of 64; nb <= 128
    int v0 = (lane < nb) ? aux[lane] : 0;
    int v1 = (lane + 64 < nb) ? aux[lane + 64] : 0;
    int s0 = v0;
    for (int off = 1; off < 64; off <<= 1) { int x = __shfl_up(s0, off); if (lane >= off) s0 += x; }
    int total0 = __shfl(s0, 63);
    int s1 = v1;
    for (int off = 1; off < 64; off <<= 1) { int x = __shfl_up(s1, off); if (lane >= off) s1 += x; }
    if (lane < nb) aux[lane] = s0 - v0;
    if (lane + 64 < nb) aux[lane + 64] = total0 + s1 - v1;
}

__global__ void scan3_k(const int* __restrict__ excl, const int* __restrict__ aux,
                        int* __restrict__ offs, int* __restrict__ cursor, int N, int E) {
    int i = blockIdx.x * 1024 + threadIdx.x;
    if (i < N) {
        int v = excl[i] + aux[blockIdx.x];
        offs[i] = v;
        cursor[i] = v;
    } else if (i == N) {
        offs[N] = E;
    }
}

__global__ void scatter_k(const int* __restrict__ src, const int* __restrict__ dst,
                          int* __restrict__ cursor, int* __restrict__ esrc, int E, int N) {
    int e = blockIdx.x * 256 + threadIdx.x;
    if (e < E) {
        int d = dst[e];
        d = d < 0 ? 0 : (d >= N ? N - 1 : d);
        int s = src[e];
        s = s < 0 ? 0 : (s >= N ? N - 1 : s);
        int p = atomicAdd(&cursor[d], 1);
        esrc[p] = s;
    }
}

// ---------------- weight prepack (fp32 -> bf16 MFMA-fragment order) ----------------
// Wf[(kq*DO + n)*8 + j] = bf16(W[(kq*8 + j)*DO + n])   (k = kq*8 + j)
__global__ void prepack_k(const float* __restrict__ W, u16* __restrict__ Wf, int DO, int total) {
    int idx = blockIdx.x * 256 + threadIdx.x;
    if (idx >= total) return;
    int j = idx & 7;
    int t = idx >> 3;
    int n = t % DO;
    int kq = t / DO;
    Wf[idx] = f2bf(W[(size_t)(kq * 8 + j) * DO + n]);
}

// ---------------- GEMM: H(fp32) = X @ W, bf16 MFMA, fp32 accumulate ----------------
// F32IN: X is fp32 (cast to bf16 during LDS staging). Else X is bf16 (u16).
template <int K, int DO, bool F32IN>
__global__ __launch_bounds__(256, 2) void gemm_k(const void* __restrict__ Xv,
                                                 const u16* __restrict__ Wf,
                                                 float* __restrict__ H, int nrow) {
    constexpr int BM = 128, BK = 64;
    __shared__ alignas(16) u16 At[BM * BK];  // 16 KB bf16, XOR-swizzled 16B units
    const int tid = threadIdx.x;
    const int wave = tid >> 6, lane = tid & 63;
    const int quad = lane >> 4, l16 = lane & 15;
    const int row0 = blockIdx.x * BM;

    floatx4 acc[2][DO / 16];
#pragma unroll
    for (int a = 0; a < 2; a++)
#pragma unroll
        for (int b = 0; b < DO / 16; b++) acc[a][b] = floatx4{0.f, 0.f, 0.f, 0.f};

    for (int kt = 0; kt < K / BK; ++kt) {
        __syncthreads();
#pragma unroll
        for (int i = 0; i < 4; ++i) {
            int seg = tid + i * 256;          // 1024 segments of 8 k-elements
            int r = seg >> 3, c = seg & 7;
            int gr = row0 + r;
            gr = gr < nrow ? gr : nrow - 1;   // clamp (pad rows discarded on store)
            u16 pk[8];
            if (F32IN) {
                const float* X = (const float*)Xv;
                float4 v0 = *(const float4*)(X + (size_t)gr * K + kt * BK + c * 8);
                float4 v1 = *(const float4*)(X + (size_t)gr * K + kt * BK + c * 8 + 4);
                pk[0] = f2bf(v0.x); pk[1] = f2bf(v0.y); pk[2] = f2bf(v0.z); pk[3] = f2bf(v0.w);
                pk[4] = f2bf(v1.x); pk[5] = f2bf(v1.y); pk[6] = f2bf(v1.z); pk[7] = f2bf(v1.w);
                *(int4*)(At + r * BK + (c ^ (r & 7)) * 8) = *(const int4*)pk;
            } else {
                const u16* X = (const u16*)Xv;
                int4 v = *(const int4*)(X + (size_t)gr * K + kt * BK + c * 8);
                *(int4*)(At + r * BK + (c ^ (r & 7)) * 8) = v;
            }
        }
        __syncthreads();
#pragma unroll
        for (int ks = 0; ks < 2; ++ks) {
            short8 bfr[DO / 16];
            int kq = kt * 8 + ks * 4 + quad;
#pragma unroll
            for (int ct = 0; ct < DO / 16; ++ct)
                bfr[ct] = *(const short8*)(Wf + ((size_t)kq * DO + ct * 16 + l16) * 8);
#pragma unroll
            for (int rt = 0; rt < 2; ++rt) {
                int row = wave * 32 + rt * 16 + l16;
                int unit = (ks * 4 + quad) ^ (row & 7);
                short8 afr = *(const short8*)(At + row * BK + unit * 8);
#pragma unroll
                for (int ct = 0; ct < DO / 16; ++ct)
                    acc[rt][ct] =
                        __builtin_amdgcn_mfma_f32_16x16x32_bf16(afr, bfr[ct], acc[rt][ct], 0, 0, 0);
            }
        }
    }
    // C/D layout: col = lane&15, row = quad*4 + r   [m89/m91 verified]
#pragma unroll
    for (int rt = 0; rt < 2; ++rt)
#pragma unroll
        for (int r = 0; r < 4; ++r) {
            int grow = row0 + wave * 32 + rt * 16 + quad * 4 + r;
            if (grow < nrow) {
#pragma unroll
                for (int ct = 0; ct < DO / 16; ++ct)
                    H[(size_t)grow * DO + ct * 16 + l16] = acc[rt][ct][r];
            }
        }
}

// ---------------- per-node attention dots: alpha_s[n], alpha_d[n] (fp32) ----------------
template <int DO>
__global__ __launch_bounds__(256) void alphas_k(const float* __restrict__ H,
                                                const float* __restrict__ a_src,
                                                const float* __restrict__ a_dst,
                                                float* __restrict__ AS, float* __restrict__ AD,
                                                int N) {
    int wave = threadIdx.x >> 6, lane = threadIdx.x & 63;
    int n = blockIdx.x * 4 + wave;
    if (n >= N) return;
    float ps = 0.f, pd = 0.f;
#pragma unroll
    for (int f = lane; f < DO; f += 64) {
        float h = H[(size_t)n * DO + f];
        ps += h * a_src[f];
        pd += h * a_dst[f];
    }
    for (int o = 32; o; o >>= 1) {
        ps += __shfl_xor(ps, o);
        pd += __shfl_xor(pd, o);
    }
    if (lane == 0) {
        AS[n] = ps;
        AD[n] = pd;
    }
}

// ---------------- fused segment softmax + aggregate (one wave per dst node) ----------------
// OUTB: write bf16 (next-layer GEMM input) vs fp32 (final output).
template <int DO, bool OUTB>
__global__ __launch_bounds__(256) void agg_k(const float* __restrict__ H,
                                             const float* __restrict__ AS,
                                             const float* __restrict__ AD,
                                             const int* __restrict__ offs,
                                             const int* __restrict__ esrc,
                                             const float* __restrict__ bias,
                                             void* __restrict__ OUT, int N) {
    const int wave = threadIdx.x >> 6, lane = threadIdx.x & 63;
    const int d = blockIdx.x * 4 + wave;
    if (d >= N) return;
    const int o0 = offs[d];
    const int deg = offs[d + 1] - o0;  // real in-edges
    const int tot = deg + 1;           // + self loop
    const float ad = AD[d];

    // pass 1: segment max of leaky_relu(as[src]+ad, 0.2)
    float mx = -1e30f;
    for (int i = lane; i < tot; i += 64) {
        int s = (i < deg) ? esrc[o0 + i] : d;
        float lg = AS[s] + ad;
        lg = lg > 0.f ? lg : lg * 0.2f;
        mx = fmaxf(mx, lg);
    }
    for (int o = 32; o; o >>= 1) mx = fmaxf(mx, __shfl_xor(mx, o));

    // pass 2: sum of exp
    float sum = 0.f;
    for (int i = lane; i < tot; i += 64) {
        int s = (i < deg) ? esrc[o0 + i] : d;
        float lg = AS[s] + ad;
        lg = lg > 0.f ? lg : lg * 0.2f;
        sum += __expf(lg - mx);
    }
    for (int o = 32; o; o >>= 1) sum += __shfl_xor(sum, o);
    const float inv = 1.f / sum;  // sum >= 1 (max element contributes exp(0))

    // pass 3: shfl-broadcast weights + coalesced fp32 feature aggregation
    float acc0 = 0.f, acc1 = 0.f;
    for (int c0 = 0; c0 < tot; c0 += 64) {
        int i = c0 + lane;
        float w = 0.f;
        int s = d;
        if (i < tot) {
            s = (i < deg) ? esrc[o0 + i] : d;
            float lg = AS[s] + ad;
            lg = lg > 0.f ? lg : lg * 0.2f;
            w = __expf(lg - mx) * inv;
        }
        int cn = tot - c0;
        cn = cn < 64 ? cn : 64;
        for (int l = 0; l < cn; ++l) {
            float wl = __shfl(w, l);
            int sl = __shfl(s, l);
            if (DO == 128) {
                float2 hv = *(const float2*)(H + (size_t)sl * 128 + 2 * lane);
                acc0 = fmaf(wl, hv.x, acc0);
                acc1 = fmaf(wl, hv.y, acc1);
            } else {
                acc0 = fmaf(wl, H[(size_t)sl * DO + lane], acc0);
            }
        }
    }

    // epilogue: + bias, leaky_relu(0.25), store
    if (DO == 128) {
        int f = 2 * lane;
        float v0 = acc0 + bias[f];
        float v1 = acc1 + bias[f + 1];
        v0 = v0 > 0.f ? v0 : v0 * 0.25f;
        v1 = v1 > 0.f ? v1 : v1 * 0.25f;
        if (OUTB) {
            u32 packed = (u32)f2bf(v0) | ((u32)f2bf(v1) << 16);
            ((u32*)OUT)[(size_t)d * 64 + lane] = packed;
        } else {
            ((float2*)OUT)[(size_t)d * 64 + lane] = float2{v0, v1};
        }
    } else {
        float v0 = acc0 + bias[lane];
        v0 = v0 > 0.f ? v0 : v0 * 0.25f;
        if (OUTB) {
            ((u16*)OUT)[(size_t)d * DO + lane] = f2bf(v0);
        } else {
            ((float*)OUT)[(size_t)d * DO + lane] = v0;
        }
    }
}

// ---------------- launch ----------------

extern "C" void kernel_launch(void* const* d_in, const int* in_sizes, int n_in,
                              void* d_out, int out_size, void* d_ws, size_t ws_size,
                              hipStream_t stream) {
    const int N = in_sizes[0] / 512;  // 100000
    const int E = in_sizes[1] / 2;    // 1600000

    const float* data = (const float*)d_in[0];
    const int* adj = (const int*)d_in[1];
    const float* W1 = (const float*)d_in[2];
    const float* as1 = (const float*)d_in[3];
    const float* ad1 = (const float*)d_in[4];
    const float* b1 = (const float*)d_in[5];
    const float* W2 = (const float*)d_in[6];
    const float* as2 = (const float*)d_in[7];
    const float* ad2 = (const float*)d_in[8];
    const float* b2 = (const float*)d_in[9];
    const float* W3 = (const float*)d_in[10];
    const float* as3 = (const float*)d_in[11];
    const float* ad3 = (const float*)d_in[12];
    const float* b3 = (const float*)d_in[13];

    // ---- workspace carve + budget check ----
    char* ws = (char*)d_ws;
    size_t need = 0;
    auto carve = [&](size_t bytes) {
        void* p = (void*)(ws + need);
        need += (bytes + 255) & ~(size_t)255;
        return p;
    };
    int* esrc = (int*)carve((size_t)E * 4);
    int* offs = (int*)carve((size_t)(N + 1) * 4);
    int* cursor = (int*)carve((size_t)N * 4);
    int* cnt = (int*)carve((size_t)N * 4);
    int* excl = (int*)carve((size_t)N * 4);
    int* aux = (int*)carve(1024);
    float* AS = (float*)carve((size_t)N * 4);
    float* AD = (float*)carve((size_t)N * 4);
    float* h = (float*)carve((size_t)N * 128 * 4);   // fp32 h (max DO=128)
    u16* x1 = (u16*)carve((size_t)N * 128 * 2);      // bf16 next-layer input
    u16* x2 = x1;                                    // x1 dead after layer-2 GEMM
    u16* Wf1 = (u16*)carve(512 * 128 * 2);
    u16* Wf2 = (u16*)carve(128 * 128 * 2);
    u16* Wf3 = (u16*)carve(128 * 64 * 2);

    if (need > ws_size) {
        // Diagnostic signature: absmax == ref absmax (0.2373) => ws too small.
        zero_out_k<<<(out_size + 255) / 256, 256, 0, stream>>>((float*)d_out, out_size);
        return;
    }

    const int* srcl = adj;
    const int* dstl = adj + E;

    // ---- CSR build (once, reused by all 3 layers) ----
    hipMemsetAsync(cnt, 0, (size_t)N * 4, stream);
    hist_k<<<(E + 255) / 256, 256, 0, stream>>>(dstl, cnt, E, N);
    int nb = (N + 1023) / 1024;
    scan1_k<<<nb, 1024, 0, stream>>>(cnt, excl, aux, N);
    scan2_k<<<1, 64, 0, stream>>>(aux, nb);
    scan3_k<<<nb, 1024, 0, stream>>>(excl, aux, offs, cursor, N, E);
    scatter_k<<<(E + 255) / 256, 256, 0, stream>>>(srcl, dstl, cursor, esrc, E, N);

    // ---- weight prepack (fp32 -> bf16 fragments) ----
    prepack_k<<<(512 * 128 + 255) / 256, 256, 0, stream>>>(W1, Wf1, 128, 512 * 128);
    prepack_k<<<(128 * 128 + 255) / 256, 256, 0, stream>>>(W2, Wf2, 128, 128 * 128);
    prepack_k<<<(128 * 64 + 255) / 256, 256, 0, stream>>>(W3, Wf3, 64, 128 * 64);

    const int gblk = (N + 127) / 128;
    const int nblk = (N + 3) / 4;

    // ---- layer 1 ----
    gemm_k<512, 128, true><<<gblk, 256, 0, stream>>>(data, Wf1, h, N);
    alphas_k<128><<<nblk, 256, 0, stream>>>(h, as1, ad1, AS, AD, N);
    agg_k<128, true><<<nblk, 256, 0, stream>>>(h, AS, AD, offs, esrc, b1, x1, N);
    // ---- layer 2 ----
    gemm_k<128, 128, false><<<gblk, 256, 0, stream>>>(x1, Wf2, h, N);
    alphas_k<128><<<nblk, 256, 0, stream>>>(h, as2, ad2, AS, AD, N);
    agg_k<128, true><<<nblk, 256, 0, stream>>>(h, AS, AD, offs, esrc, b2, x2, N);
    // ---- layer 3 ----
    gemm_k<128, 64, false><<<gblk, 256, 0, stream>>>(x2, Wf3, h, N);
    alphas_k<64><<<nblk, 256, 0, stream>>>(h, as3, ad3, AS, AD, N);
    agg_k<64, false><<<nblk, 256, 0, stream>>>(h, AS, AD, offs, esrc, b3, d_out, N);
}

// Round 4
// 925.697 us; speedup vs baseline: 1.1071x; 1.1071x over previous
//
#include <hip/hip_runtime.h>

typedef unsigned short u16;
typedef unsigned int u32;
typedef short short8 __attribute__((ext_vector_type(8)));
typedef float floatx4 __attribute__((ext_vector_type(4)));

__device__ __forceinline__ float bf2f(u16 x) { return __uint_as_float(((u32)x) << 16); }
__device__ __forceinline__ u16 f2bf(float x) {
    u32 u = __float_as_uint(x);
    u += 0x7fffu + ((u >> 16) & 1u);
    return (u16)(u >> 16);
}

// ---------------- diagnostic: zero the output (fp32) ----------------
__global__ void zero_out_k(float* __restrict__ out, int n) {
    int i = blockIdx.x * 256 + threadIdx.x;
    if (i < n) out[i] = 0.f;
}

// ---------------- CSR build: histogram, scan, scatter ----------------

__global__ void hist_k(const int* __restrict__ dst, int* __restrict__ cnt, int E, int N) {
    int e = blockIdx.x * 256 + threadIdx.x;
    if (e < E) {
        int d = dst[e];
        d = d < 0 ? 0 : (d >= N ? N - 1 : d);
        atomicAdd(&cnt[d], 1);
    }
}

__global__ void scan1_k(const int* __restrict__ cnt, int* __restrict__ excl,
                        int* __restrict__ aux, int N) {
    __shared__ int tmp[1024];
    int t = threadIdx.x;
    int i = blockIdx.x * 1024 + t;
    int v = (i < N) ? cnt[i] : 0;
    tmp[t] = v;
    __syncthreads();
    for (int off = 1; off < 1024; off <<= 1) {
        int x = (t >= off) ? tmp[t - off] : 0;
        __syncthreads();
        tmp[t] += x;
        __syncthreads();
    }
    if (i < N) excl[i] = tmp[t] - v;
    if (t == 1023) aux[blockIdx.x] = tmp[t];
}

__global__ void scan2_k(int* __restrict__ aux, int nb) {
    int lane = threadIdx.x;  // single block of 64; nb <= 128
    int v0 = (lane < nb) ? aux[lane] : 0;
    int v1 = (lane + 64 < nb) ? aux[lane + 64] : 0;
    int s0 = v0;
    for (int off = 1; off < 64; off <<= 1) { int x = __shfl_up(s0, off); if (lane >= off) s0 += x; }
    int total0 = __shfl(s0, 63);
    int s1 = v1;
    for (int off = 1; off < 64; off <<= 1) { int x = __shfl_up(s1, off); if (lane >= off) s1 += x; }
    if (lane < nb) aux[lane] = s0 - v0;
    if (lane + 64 < nb) aux[lane + 64] = total0 + s1 - v1;
}

__global__ void scan3_k(const int* __restrict__ excl, const int* __restrict__ aux,
                        int* __restrict__ offs, int* __restrict__ cursor, int N, int E) {
    int i = blockIdx.x * 1024 + threadIdx.x;
    if (i < N) {
        int v = excl[i] + aux[blockIdx.x];
        offs[i] = v;
        cursor[i] = v;
    } else if (i == N) {
        offs[N] = E;
    }
}

__global__ void scatter_k(const int* __restrict__ src, const int* __restrict__ dst,
                          int* __restrict__ cursor, int* __restrict__ esrc, int E, int N) {
    int e = blockIdx.x * 256 + threadIdx.x;
    if (e < E) {
        int d = dst[e];
        d = d < 0 ? 0 : (d >= N ? N - 1 : d);
        int s = src[e];
        s = s < 0 ? 0 : (s >= N ? N - 1 : s);
        int p = atomicAdd(&cursor[d], 1);
        esrc[p] = s;
    }
}

// ---------------- weight prepack (fp32 -> bf16 MFMA-fragment order) ----------------
// Wf[(kq*DO + n)*8 + j] = bf16(W[(kq*8 + j)*DO + n])   (k = kq*8 + j)
__global__ void prepack_k(const float* __restrict__ W, u16* __restrict__ Wf, int DO, int total) {
    int idx = blockIdx.x * 256 + threadIdx.x;
    if (idx >= total) return;
    int j = idx & 7;
    int t = idx >> 3;
    int n = t % DO;
    int kq = t / DO;
    Wf[idx] = f2bf(W[(size_t)(kq * 8 + j) * DO + n]);
}

// ---------------- GEMM + fused alpha dots ----------------
// H = X @ W (bf16 MFMA, fp32 acc); AS/AD = H . a_src/a_dst from fp32 accs.
// F32IN: X fp32 (convert during staging) else bf16. H32: store H fp32 else bf16.
template <int K, int DO, bool F32IN, bool H32>
__global__ __launch_bounds__(256, 2) void gemm_k(const void* __restrict__ Xv,
                                                 const u16* __restrict__ Wf,
                                                 void* __restrict__ Hv,
                                                 const float* __restrict__ a_src,
                                                 const float* __restrict__ a_dst,
                                                 float* __restrict__ AS,
                                                 float* __restrict__ AD, int nrow) {
    constexpr int BM = 128, BK = 64;
    __shared__ alignas(16) u16 At[BM * BK];  // 16 KB bf16, XOR-swizzled 16B units
    const int tid = threadIdx.x;
    const int wave = tid >> 6, lane = tid & 63;
    const int quad = lane >> 4, l16 = lane & 15;
    const int row0 = blockIdx.x * BM;

    floatx4 acc[2][DO / 16];
#pragma unroll
    for (int a = 0; a < 2; a++)
#pragma unroll
        for (int b = 0; b < DO / 16; b++) acc[a][b] = floatx4{0.f, 0.f, 0.f, 0.f};

    for (int kt = 0; kt < K / BK; ++kt) {
        __syncthreads();
#pragma unroll
        for (int i = 0; i < 4; ++i) {
            int seg = tid + i * 256;          // 1024 segments of 8 k-elements
            int r = seg >> 3, c = seg & 7;
            int gr = row0 + r;
            gr = gr < nrow ? gr : nrow - 1;   // clamp (pad rows discarded on store)
            u16 pk[8];
            if (F32IN) {
                const float* X = (const float*)Xv;
                float4 v0 = *(const float4*)(X + (size_t)gr * K + kt * BK + c * 8);
                float4 v1 = *(const float4*)(X + (size_t)gr * K + kt * BK + c * 8 + 4);
                pk[0] = f2bf(v0.x); pk[1] = f2bf(v0.y); pk[2] = f2bf(v0.z); pk[3] = f2bf(v0.w);
                pk[4] = f2bf(v1.x); pk[5] = f2bf(v1.y); pk[6] = f2bf(v1.z); pk[7] = f2bf(v1.w);
                *(int4*)(At + r * BK + (c ^ (r & 7)) * 8) = *(const int4*)pk;
            } else {
                const u16* X = (const u16*)Xv;
                int4 v = *(const int4*)(X + (size_t)gr * K + kt * BK + c * 8);
                *(int4*)(At + r * BK + (c ^ (r & 7)) * 8) = v;
            }
        }
        __syncthreads();
#pragma unroll
        for (int ks = 0; ks < 2; ++ks) {
            short8 bfr[DO / 16];
            int kq = kt * 8 + ks * 4 + quad;
#pragma unroll
            for (int ct = 0; ct < DO / 16; ++ct)
                bfr[ct] = *(const short8*)(Wf + ((size_t)kq * DO + ct * 16 + l16) * 8);
#pragma unroll
            for (int rt = 0; rt < 2; ++rt) {
                int row = wave * 32 + rt * 16 + l16;
                int unit = (ks * 4 + quad) ^ (row & 7);
                short8 afr = *(const short8*)(At + row * BK + unit * 8);
#pragma unroll
                for (int ct = 0; ct < DO / 16; ++ct)
                    acc[rt][ct] =
                        __builtin_amdgcn_mfma_f32_16x16x32_bf16(afr, bfr[ct], acc[rt][ct], 0, 0, 0);
            }
        }
    }
    // Epilogue. C/D layout: col = ct*16 + l16, row = quad*4 + r  [m89/m91 verified].
    // Fused alpha dots: partial over this lane's 8 (or 4) cols, reduce across l16 group.
    float asv[DO / 16], adv[DO / 16];
#pragma unroll
    for (int ct = 0; ct < DO / 16; ++ct) {
        asv[ct] = a_src[ct * 16 + l16];
        adv[ct] = a_dst[ct * 16 + l16];
    }
#pragma unroll
    for (int rt = 0; rt < 2; ++rt)
#pragma unroll
        for (int r = 0; r < 4; ++r) {
            int grow = row0 + wave * 32 + rt * 16 + quad * 4 + r;
            bool ok = grow < nrow;
            float ps = 0.f, pd = 0.f;
#pragma unroll
            for (int ct = 0; ct < DO / 16; ++ct) {
                float v = acc[rt][ct][r];
                ps = fmaf(v, asv[ct], ps);
                pd = fmaf(v, adv[ct], pd);
                if (ok) {
                    if (H32)
                        ((float*)Hv)[(size_t)grow * DO + ct * 16 + l16] = v;
                    else
                        ((u16*)Hv)[(size_t)grow * DO + ct * 16 + l16] = f2bf(v);
                }
            }
            // reduce over the 16-lane col group (xor bits 0-3 stay within quad)
#pragma unroll
            for (int o = 1; o < 16; o <<= 1) {
                ps += __shfl_xor(ps, o);
                pd += __shfl_xor(pd, o);
            }
            if (ok && l16 == 0) {
                AS[grow] = ps;
                AD[grow] = pd;
            }
        }
}

// ---------------- fused segment softmax + aggregate (one wave per dst node) ----------------
// HB: h rows are bf16 (else fp32). OUTB: write bf16 packed (else fp32).
template <int DO, bool HB, bool OUTB>
__global__ __launch_bounds__(256) void agg_k(const void* __restrict__ Hv,
                                             const float* __restrict__ AS,
                                             const float* __restrict__ AD,
                                             const int* __restrict__ offs,
                                             const int* __restrict__ esrc,
                                             const float* __restrict__ bias,
                                             void* __restrict__ OUT, int N) {
    const int wave = threadIdx.x >> 6, lane = threadIdx.x & 63;
    const int d = blockIdx.x * 4 + wave;
    if (d >= N) return;
    const int o0 = offs[d];
    const int deg = offs[d + 1] - o0;  // real in-edges
    const int tot = deg + 1;           // + self loop
    const float ad = AD[d];

    float acc0 = 0.f, acc1 = 0.f;

    if (tot <= 64) {
        // ---- fast path: whole segment resident in one wave, single gather pass ----
        int s = (lane < deg) ? esrc[o0 + lane] : d;  // lane==deg -> self loop
        bool valid = lane < tot;
        float lg = AS[s] + ad;
        lg = lg > 0.f ? lg : lg * 0.2f;
        float lgv = valid ? lg : -1e30f;
        float m = lgv;
        for (int o = 32; o; o >>= 1) m = fmaxf(m, __shfl_xor(m, o));
        float e = valid ? __expf(lg - m) : 0.f;
        float sum = e;
        for (int o = 32; o; o >>= 1) sum += __shfl_xor(sum, o);
        float w = e * (1.f / sum);
        for (int l = 0; l < tot; ++l) {
            float wl = __shfl(w, l);
            int sl = __shfl(s, l);
            if (DO == 128) {
                if (HB) {
                    u32 hv = ((const u32*)Hv)[(size_t)sl * 64 + lane];
                    acc0 = fmaf(wl, bf2f((u16)hv), acc0);
                    acc1 = fmaf(wl, bf2f((u16)(hv >> 16)), acc1);
                } else {
                    float2 hv = ((const float2*)Hv)[(size_t)sl * 64 + lane];
                    acc0 = fmaf(wl, hv.x, acc0);
                    acc1 = fmaf(wl, hv.y, acc1);
                }
            } else {
                if (HB) {
                    acc0 = fmaf(wl, bf2f(((const u16*)Hv)[(size_t)sl * DO + lane]), acc0);
                } else {
                    acc0 = fmaf(wl, ((const float*)Hv)[(size_t)sl * DO + lane], acc0);
                }
            }
        }
    } else {
        // ---- general path (deg > 63): 3-pass ----
        float mx = -1e30f;
        for (int i = lane; i < tot; i += 64) {
            int s = (i < deg) ? esrc[o0 + i] : d;
            float lg = AS[s] + ad;
            lg = lg > 0.f ? lg : lg * 0.2f;
            mx = fmaxf(mx, lg);
        }
        for (int o = 32; o; o >>= 1) mx = fmaxf(mx, __shfl_xor(mx, o));
        float sum = 0.f;
        for (int i = lane; i < tot; i += 64) {
            int s = (i < deg) ? esrc[o0 + i] : d;
            float lg = AS[s] + ad;
            lg = lg > 0.f ? lg : lg * 0.2f;
            sum += __expf(lg - mx);
        }
        for (int o = 32; o; o >>= 1) sum += __shfl_xor(sum, o);
        const float inv = 1.f / sum;
        for (int c0 = 0; c0 < tot; c0 += 64) {
            int i = c0 + lane;
            float w = 0.f;
            int s = d;
            if (i < tot) {
                s = (i < deg) ? esrc[o0 + i] : d;
                float lg = AS[s] + ad;
                lg = lg > 0.f ? lg : lg * 0.2f;
                w = __expf(lg - mx) * inv;
            }
            int cn = tot - c0;
            cn = cn < 64 ? cn : 64;
            for (int l = 0; l < cn; ++l) {
                float wl = __shfl(w, l);
                int sl = __shfl(s, l);
                if (DO == 128) {
                    if (HB) {
                        u32 hv = ((const u32*)Hv)[(size_t)sl * 64 + lane];
                        acc0 = fmaf(wl, bf2f((u16)hv), acc0);
                        acc1 = fmaf(wl, bf2f((u16)(hv >> 16)), acc1);
                    } else {
                        float2 hv = ((const float2*)Hv)[(size_t)sl * 64 + lane];
                        acc0 = fmaf(wl, hv.x, acc0);
                        acc1 = fmaf(wl, hv.y, acc1);
                    }
                } else {
                    if (HB) {
                        acc0 = fmaf(wl, bf2f(((const u16*)Hv)[(size_t)sl * DO + lane]), acc0);
                    } else {
                        acc0 = fmaf(wl, ((const float*)Hv)[(size_t)sl * DO + lane], acc0);
                    }
                }
            }
        }
    }

    // epilogue: + bias, leaky_relu(0.25), store
    if (DO == 128) {
        int f = 2 * lane;
        float v0 = acc0 + bias[f];
        float v1 = acc1 + bias[f + 1];
        v0 = v0 > 0.f ? v0 : v0 * 0.25f;
        v1 = v1 > 0.f ? v1 : v1 * 0.25f;
        if (OUTB) {
            u32 packed = (u32)f2bf(v0) | ((u32)f2bf(v1) << 16);
            ((u32*)OUT)[(size_t)d * 64 + lane] = packed;
        } else {
            ((float2*)OUT)[(size_t)d * 64 + lane] = float2{v0, v1};
        }
    } else {
        float v0 = acc0 + bias[lane];
        v0 = v0 > 0.f ? v0 : v0 * 0.25f;
        if (OUTB) {
            ((u16*)OUT)[(size_t)d * DO + lane] = f2bf(v0);
        } else {
            ((float*)OUT)[(size_t)d * DO + lane] = v0;
        }
    }
}

// ---------------- launch ----------------

extern "C" void kernel_launch(void* const* d_in, const int* in_sizes, int n_in,
                              void* d_out, int out_size, void* d_ws, size_t ws_size,
                              hipStream_t stream) {
    const int N = in_sizes[0] / 512;  // 100000
    const int E = in_sizes[1] / 2;    // 1600000

    const float* data = (const float*)d_in[0];
    const int* adj = (const int*)d_in[1];
    const float* W1 = (const float*)d_in[2];
    const float* as1 = (const float*)d_in[3];
    const float* ad1 = (const float*)d_in[4];
    const float* b1 = (const float*)d_in[5];
    const float* W2 = (const float*)d_in[6];
    const float* as2 = (const float*)d_in[7];
    const float* ad2 = (const float*)d_in[8];
    const float* b2 = (const float*)d_in[9];
    const float* W3 = (const float*)d_in[10];
    const float* as3 = (const float*)d_in[11];
    const float* ad3 = (const float*)d_in[12];
    const float* b3 = (const float*)d_in[13];

    // ---- workspace carve + budget check ----
    char* ws = (char*)d_ws;
    size_t need = 0;
    auto carve = [&](size_t bytes) {
        void* p = (void*)(ws + need);
        need += (bytes + 255) & ~(size_t)255;
        return p;
    };
    int* esrc = (int*)carve((size_t)E * 4);
    int* offs = (int*)carve((size_t)(N + 1) * 4);
    int* cursor = (int*)carve((size_t)N * 4);
    int* cnt = (int*)carve((size_t)N * 4);
    int* excl = (int*)carve((size_t)N * 4);
    int* aux = (int*)carve(1024);
    float* AS = (float*)carve((size_t)N * 4);
    float* AD = (float*)carve((size_t)N * 4);
    u16* Hb = (u16*)carve((size_t)N * 128 * 2);  // bf16 h (layers 1-2)
    float* H32 = (float*)Hb;                     // fp32 h for layer 3 (DO=64): same 25.6 MB
    u16* x1 = (u16*)carve((size_t)N * 128 * 2);  // bf16 next-layer input
    u16* x2 = x1;                                // x1 dead after layer-2 GEMM
    u16* Wf1 = (u16*)carve(512 * 128 * 2);
    u16* Wf2 = (u16*)carve(128 * 128 * 2);
    u16* Wf3 = (u16*)carve(128 * 64 * 2);

    if (need > ws_size) {
        // Diagnostic signature: absmax == ref absmax (0.2373) => ws too small.
        zero_out_k<<<(out_size + 255) / 256, 256, 0, stream>>>((float*)d_out, out_size);
        return;
    }

    const int* srcl = adj;
    const int* dstl = adj + E;

    // ---- CSR build (once, reused by all 3 layers) ----
    hipMemsetAsync(cnt, 0, (size_t)N * 4, stream);
    hist_k<<<(E + 255) / 256, 256, 0, stream>>>(dstl, cnt, E, N);
    int nb = (N + 1023) / 1024;
    scan1_k<<<nb, 1024, 0, stream>>>(cnt, excl, aux, N);
    scan2_k<<<1, 64, 0, stream>>>(aux, nb);
    scan3_k<<<nb, 1024, 0, stream>>>(excl, aux, offs, cursor, N, E);
    scatter_k<<<(E + 255) / 256, 256, 0, stream>>>(srcl, dstl, cursor, esrc, E, N);

    // ---- weight prepack (fp32 -> bf16 fragments) ----
    prepack_k<<<(512 * 128 + 255) / 256, 256, 0, stream>>>(W1, Wf1, 128, 512 * 128);
    prepack_k<<<(128 * 128 + 255) / 256, 256, 0, stream>>>(W2, Wf2, 128, 128 * 128);
    prepack_k<<<(128 * 64 + 255) / 256, 256, 0, stream>>>(W3, Wf3, 64, 128 * 64);

    const int gblk = (N + 127) / 128;
    const int nblk = (N + 3) / 4;

    // ---- layer 1 ----
    gemm_k<512, 128, true, false><<<gblk, 256, 0, stream>>>(data, Wf1, Hb, as1, ad1, AS, AD, N);
    agg_k<128, true, true><<<nblk, 256, 0, stream>>>(Hb, AS, AD, offs, esrc, b1, x1, N);
    // ---- layer 2 ----
    gemm_k<128, 128, false, false><<<gblk, 256, 0, stream>>>(x1, Wf2, Hb, as2, ad2, AS, AD, N);
    agg_k<128, true, true><<<nblk, 256, 0, stream>>>(Hb, AS, AD, offs, esrc, b2, x2, N);
    // ---- layer 3 (fp32 h for final accuracy; 256 B/row gather either way) ----
    gemm_k<128, 64, false, true><<<gblk, 256, 0, stream>>>(x2, Wf3, H32, as3, ad3, AS, AD, N);
    agg_k<64, false, false><<<nblk, 256, 0, stream>>>(H32, AS, AD, offs, esrc, b3, d_out, N);
}